// Round 15
// baseline (109.936 us; speedup 1.0000x reference)
//
#include <hip/hip_runtime.h>

typedef short short8 __attribute__((ext_vector_type(8)));
typedef float f32x4 __attribute__((ext_vector_type(4)));

#define EPS 0.012f   // > 4x worst-case bf16-split dist error

__device__ __forceinline__ unsigned short rne_bf16(float v) {
    unsigned u = __float_as_uint(v);
    unsigned r = u + 0x7FFFu + ((u >> 16) & 1u);
    return (unsigned short)(r >> 16);
}
__device__ __forceinline__ float bf16_to_f(unsigned short h) {
    return __uint_as_float(((unsigned)h) << 16);
}

#define MFMA(a,b,c) __builtin_amdgcn_mfma_f32_16x16x32_bf16((a),(b),(c),0,0,0)

// LDS-handoff barrier: dist stores stay in flight (no vmcnt drain in main loop)
#define LIGHT_BARRIER() do {                                   \
    asm volatile("s_waitcnt lgkmcnt(0)" ::: "memory");         \
    __builtin_amdgcn_s_barrier();                              \
    __builtin_amdgcn_sched_barrier(0);                         \
} while (0)

// ---- prep: codebook * (-2) -> bf16 hi/lo (exact pow2 scale) + unscaled norms ----
__global__ __launch_bounds__(64) void prep_kernel(
    const float* __restrict__ emb, unsigned short* __restrict__ whi,
    unsigned short* __restrict__ wlo, float* __restrict__ wee)
{
    const int k = blockIdx.x * 64 + threadIdx.x;   // 512 rows
    const float* src = emb + k * 64;
    float nrm = 0.f;
    #pragma unroll
    for (int g = 0; g < 8; ++g) {
        float4 v0 = *(const float4*)(src + g * 8);
        float4 v1 = *(const float4*)(src + g * 8 + 4);
        float vv[8] = {v0.x, v0.y, v0.z, v0.w, v1.x, v1.y, v1.z, v1.w};
        short8 h8, l8;
        #pragma unroll
        for (int i = 0; i < 8; ++i) {
            nrm = fmaf(vv[i], vv[i], nrm);
            float v2 = -2.0f * vv[i];                   // exact
            unsigned short hb = rne_bf16(v2);
            h8[i] = (short)hb;
            l8[i] = (short)rne_bf16(v2 - bf16_to_f(hb));
        }
        *(short8*)(whi + k * 64 + g * 8) = h8;
        *(short8*)(wlo + k * 64 + g * 8) = l8;
    }
    wee[k] = nrm;
}

#define DT 36   // dtile row stride in floats: 144B (16B-aligned, rows shift 4 banks)

__global__ __launch_bounds__(256, 4) void vq_kernel(
    const float* __restrict__ x, const float* __restrict__ emb,
    const unsigned short* __restrict__ whi, const unsigned short* __restrict__ wlo,
    const float* __restrict__ wee,
    float* __restrict__ out_q, float* __restrict__ out_enc,
    float* __restrict__ out_dist, float* __restrict__ out_loss)
{
    __shared__ __align__(16) unsigned short ehi[2][32 * 64];  // 4 KB x2 dbuf, swizzled
    __shared__ __align__(16) unsigned short elo[2][32 * 64];  // 4 KB x2
    __shared__ __align__(16) float dtile[4][16 * DT];         // per-wave dist tile
    __shared__ __align__(16) float ee_s[512];                 // ||e_k||^2 (unscaled)
    __shared__ int   enc_s[64];
    __shared__ float red_s[4];

    const int t   = threadIdx.x;
    // XCD-aware bijective swizzle (2048 % 8 == 0): each XCD owns a contiguous
    // 256-block span -> contiguous 32 MB dist region per XCD L2.
    const int bid = ((blockIdx.x & 7) << 8) | (blockIdx.x >> 3);
    const int n_base = bid * 64;
    const size_t xbase = (size_t)(bid >> 6) * 262144 + (size_t)(bid & 63) * 64;
    const int l  = t & 63;
    const int wv = t >> 6;                   // 4 waves; wave owns rows wv*16..+15

    ee_s[t]       = wee[t];
    ee_s[t + 256] = wee[t + 256];

    // ---- x prologue: per-lane fragment load straight from global, no LDS ----
    // B layout (32x16): col = lane&15 (x row), d = (lane>>4)*8 + i  (+32 for frag1)
    const int myw = wv * 16 + (l & 15);      // this lane's row (= w)
    const int g8  = (l >> 4) * 8;
    float va[16];
    {
        const float* xp = x + xbase + myw;
        #pragma unroll
        for (int i = 0; i < 8; ++i) {
            va[i]     = xp[(size_t)(g8 + i) * 4096];
            va[8 + i] = xp[(size_t)(g8 + 32 + i) * 4096];
        }
    }
    short8 xhi0, xhi1, xlo0, xlo1;
    float xx = 0.f;
    #pragma unroll
    for (int i = 0; i < 8; ++i) {
        xx = fmaf(va[i], va[i], xx);
        xx = fmaf(va[8 + i], va[8 + i], xx);
        unsigned short hb = rne_bf16(va[i]);
        xhi0[i] = (short)hb; xlo0[i] = (short)rne_bf16(va[i] - bf16_to_f(hb));
        unsigned short hb2 = rne_bf16(va[8 + i]);
        xhi1[i] = (short)hb2; xlo1[i] = (short)rne_bf16(va[8 + i] - bf16_to_f(hb2));
    }
    xx += __shfl_xor(xx, 16, 64);            // 4 lane-groups cover disjoint d-ranges
    xx += __shfl_xor(xx, 32, 64);
    const f32x4 xx4 = {xx, xx, xx, xx};

    // ---- chunked (32 k-rows) double-buffered codebook staging ----
    short8 sh, sl;
    const int skr = t >> 3;                  // 0..31
    const int sd0 = (t & 7) * 8;
    const int sidx = skr * 64 + (sd0 ^ ((skr & 7) << 3));
    #define STAGE_LOAD(c) {                                                    \
        sh = *(const short8*)(whi + (size_t)(((c) * 32 + skr) * 64 + sd0));    \
        sl = *(const short8*)(wlo + (size_t)(((c) * 32 + skr) * 64 + sd0));    \
    }
    #define STAGE_WRITE(bufi) {                                                \
        *(short8*)&ehi[bufi][sidx] = sh;                                       \
        *(short8*)&elo[bufi][sidx] = sl;                                       \
    }

    STAGE_LOAD(0); STAGE_WRITE(0);
    float m1 = 3.4e38f, m2 = 3.4e38f; int k1 = 0;
    const int colb = (l >> 4) * 4;           // lane's k sub-base within a 16-k tile
    float* dwv = dtile[wv];
    __syncthreads();

    // ---- main loop: 16 chunks x 2 k-tiles; MFMA emits -2*dot; val IS dist ----
    #pragma unroll 2
    for (int c = 0; c < 16; ++c) {
        if (c < 15) STAGE_LOAD(c + 1);       // latency hides under compute
        const int bufi = c & 1;
        #pragma unroll
        for (int kti = 0; kti < 2; ++kti) {
            const int krl = kti * 16 + (l & 15);     // codebook row in chunk (A row)
            const int sw  = (krl & 7) << 3;
            const int bix = krl * 64;
            short8 ch0 = *(short8*)&ehi[bufi][bix + (g8 ^ sw)];
            short8 ch1 = *(short8*)&ehi[bufi][bix + ((g8 + 32) ^ sw)];
            short8 cl0 = *(short8*)&elo[bufi][bix + (g8 ^ sw)];
            short8 cl1 = *(short8*)&elo[bufi][bix + ((g8 + 32) ^ sw)];
            const int kb = c * 32 + kti * 16 + colb;   // lane's 4 k's: kb..kb+3
            f32x4 accA = *(const f32x4*)&ee_s[kb];     // init C = ||e||^2
            f32x4 accB = xx4;                          // init C = ||x||^2
            accA = MFMA(ch0, xhi0, accA);
            accB = MFMA(ch1, xhi1, accB);
            accA = MFMA(cl0, xhi0, accA);
            accB = MFMA(cl1, xhi1, accB);
            accA = MFMA(ch0, xlo0, accA);
            accB = MFMA(ch1, xlo1, accB);
            f32x4 dist4;
            #pragma unroll
            for (int r = 0; r < 4; ++r) {
                float dv = accA[r] + accB[r];          // xx + ee - 2*dot
                dist4[r] = dv;
                float nm2 = fmaxf(fminf(dv, m2), m1);  // med3(dv,m1,m2), m1<=m2
                k1 = (dv < m1) ? (kb | r) : k1;        // k ascending: strict < = first-min
                m1 = fminf(dv, m1);
                m2 = nm2;
            }
            // park in per-wave tile: row = l&15, quad = kti*4 + (l>>4)
            *(f32x4*)&dwv[(l & 15) * DT + (kti * 4 + (l >> 4)) * 4] = dist4;
        }
        // transpose-read + line-granular wave stores (8 rows x 128B per instr)
        #pragma unroll
        for (int p = 0; p < 2; ++p) {
            const int row = p * 8 + (l >> 3);
            const int k4  = (l & 7) * 4;
            f32x4 v = *(f32x4*)&dwv[row * DT + k4];
            *(f32x4*)(out_dist + (size_t)(n_base + wv * 16 + row) * 512 + c * 32 + k4) = v;
        }
        if (c < 15) STAGE_WRITE((c + 1) & 1);
        LIGHT_BARRIER();                     // LDS handoff only; stores stay in flight
    }

    __syncthreads();   // full drain: all dist stores visible for refine readback

    // ---- per-row argmin across the 4 k-lanes + rare candidate-only fp64 refine ----
    float* drow = out_dist + (size_t)(n_base + myw) * 512;
    float bv = m1; int bk = k1;
    {
        float ov = __shfl_xor(bv, 16, 64); int ok = __shfl_xor(bk, 16, 64);
        if (ov < bv || (ov == bv && ok < bk)) { bv = ov; bk = ok; }
        ov = __shfl_xor(bv, 32, 64); ok = __shfl_xor(bk, 32, 64);
        if (ov < bv || (ov == bv && ok < bk)) { bv = ov; bk = ok; }
    }
    const float thr = bv + EPS;
    const unsigned long long gmask = 0x0001000100010001ULL << (l & 15);
    unsigned long long b1 = __ballot(m1 <= thr);
    unsigned long long b2 = __ballot(m2 <= thr);
    int enc = bk; float lossv = bv;
    if (__popcll(b1 & gmask) > 1 || (b2 & gmask) != 0ULL) {   // column-coherent branch
        const float* dr   = drow + (l >> 4) * 128;
        const float* xcol = x + xbase + myw;
        double bestv = 1e300; int bestk = 0x7fffffff;
        #pragma unroll 1
        for (int c4 = 0; c4 < 32; ++c4) {
            float4 dv4 = *(const float4*)(dr + c4 * 4);
            float dvv[4] = {dv4.x, dv4.y, dv4.z, dv4.w};
            #pragma unroll 1
            for (int j = 0; j < 4; ++j) {
                if (dvv[j] <= thr) {
                    int k = (l >> 4) * 128 + c4 * 4 + j;
                    const float* er = emb + k * 64;
                    double s = 0.0;
                    #pragma unroll 4
                    for (int d = 0; d < 64; ++d) {
                        double df = (double)xcol[(size_t)d * 4096] - (double)er[d];
                        s += df * df;
                    }
                    if (s < bestv) { bestv = s; bestk = k; }  // ascending k, strict <
                }
            }
        }
        double ov = __shfl_xor(bestv, 16, 64); int ok = __shfl_xor(bestk, 16, 64);
        if (ov < bestv || (ov == bestv && ok < bestk)) { bestv = ov; bestk = ok; }
        ov = __shfl_xor(bestv, 32, 64); ok = __shfl_xor(bestk, 32, 64);
        if (ov < bestv || (ov == bestv && ok < bestk)) { bestv = ov; bestk = ok; }
        enc = bestk;
        if (l < 16 && enc != bk) lossv = drow[enc];
    }
    if (l < 16) {
        enc_s[myw] = enc;
        out_enc[n_base + myw] = (float)enc;
    }
    float lc = (l < 16) ? lossv : 0.f;       // row's (q-x)^2 sum == dist[row][enc]
    #pragma unroll
    for (int m = 32; m >= 1; m >>= 1) lc += __shfl_down(lc, m, 64);
    if (l == 0) red_s[wv] = lc;
    __syncthreads();
    if (t == 0)
        atomicAdd(out_loss, (red_s[0] + red_s[1] + red_s[2] + red_s[3]) * (1.0f / 8388608.0f));

    // ---- quantized gather (codebook L2-resident) + coalesced store ----
    {
        const int w  = t & 63;
        const int dg = t >> 6;               // d = dg*16..+15
        const int e  = enc_s[w];
        const float* er = emb + e * 64 + dg * 16;
        float* qp = out_q + xbase + (size_t)(dg * 16) * 4096 + w;
        #pragma unroll
        for (int qi = 0; qi < 4; ++qi) {
            float4 q4 = *(const float4*)(er + qi * 4);
            qp[(size_t)(qi * 4 + 0) * 4096] = q4.x;
            qp[(size_t)(qi * 4 + 1) * 4096] = q4.y;
            qp[(size_t)(qi * 4 + 2) * 4096] = q4.z;
            qp[(size_t)(qi * 4 + 3) * 4096] = q4.w;
        }
    }
}

extern "C" void kernel_launch(void* const* d_in, const int* in_sizes, int n_in,
                              void* d_out, int out_size, void* d_ws, size_t ws_size,
                              hipStream_t stream) {
    const float* x   = (const float*)d_in[0];   // [32,64,64,64]
    const float* emb = (const float*)d_in[1];   // [512,64]

    float* out_q    = (float*)d_out;            // 8388608
    float* out_enc  = out_q + 8388608;          // 131072
    float* out_dist = out_enc + 131072;         // 67108864
    float* out_loss = out_dist + 67108864;      // 1

    unsigned short* whi = (unsigned short*)d_ws;        // 512*64 bf16 hi of -2*emb (64 KB)
    unsigned short* wlo = whi + 32768;                  // 512*64 bf16 lo          (64 KB)
    float*          wee = (float*)(whi + 65536);        // 512 norms               (2 KB)

    hipMemsetAsync(out_loss, 0, sizeof(float), stream);
    prep_kernel<<<8, 64, 0, stream>>>(emb, whi, wlo, wee);
    vq_kernel<<<2048, 256, 0, stream>>>(x, emb, whi, wlo, wee,
                                        out_q, out_enc, out_dist, out_loss);
}

// Round 16
// 103.233 us; speedup vs baseline: 1.0649x; 1.0649x over previous
//
#include <hip/hip_runtime.h>

typedef short short8 __attribute__((ext_vector_type(8)));
typedef float f32x4 __attribute__((ext_vector_type(4)));

#define EPS 0.012f   // > 4x worst-case bf16-split dist error

__device__ __forceinline__ unsigned short rne_bf16(float v) {
    unsigned u = __float_as_uint(v);
    unsigned r = u + 0x7FFFu + ((u >> 16) & 1u);
    return (unsigned short)(r >> 16);
}
__device__ __forceinline__ float bf16_to_f(unsigned short h) {
    return __uint_as_float(((unsigned)h) << 16);
}

#define MFMA(a,b,c) __builtin_amdgcn_mfma_f32_16x16x32_bf16((a),(b),(c),0,0,0)

// LDS-handoff barrier: dist stores stay in flight (no vmcnt drain in main loop)
#define LIGHT_BARRIER() do {                                   \
    asm volatile("s_waitcnt lgkmcnt(0)" ::: "memory");         \
    __builtin_amdgcn_s_barrier();                              \
    __builtin_amdgcn_sched_barrier(0);                         \
} while (0)

// ---- prep: codebook * (-2) -> bf16 hi/lo (exact pow2 scale) + unscaled norms ----
__global__ __launch_bounds__(64) void prep_kernel(
    const float* __restrict__ emb, unsigned short* __restrict__ whi,
    unsigned short* __restrict__ wlo, float* __restrict__ wee)
{
    const int k = blockIdx.x * 64 + threadIdx.x;   // 512 rows
    const float* src = emb + k * 64;
    float nrm = 0.f;
    #pragma unroll
    for (int g = 0; g < 8; ++g) {
        float4 v0 = *(const float4*)(src + g * 8);
        float4 v1 = *(const float4*)(src + g * 8 + 4);
        float vv[8] = {v0.x, v0.y, v0.z, v0.w, v1.x, v1.y, v1.z, v1.w};
        short8 h8, l8;
        #pragma unroll
        for (int i = 0; i < 8; ++i) {
            nrm = fmaf(vv[i], vv[i], nrm);
            float v2 = -2.0f * vv[i];                   // exact
            unsigned short hb = rne_bf16(v2);
            h8[i] = (short)hb;
            l8[i] = (short)rne_bf16(v2 - bf16_to_f(hb));
        }
        *(short8*)(whi + k * 64 + g * 8) = h8;
        *(short8*)(wlo + k * 64 + g * 8) = l8;
    }
    wee[k] = nrm;
}

#define DT 36   // dtile row stride in floats: 144B (16B-aligned, rows shift 4 banks)

__global__ __launch_bounds__(256, 4) void vq_kernel(
    const float* __restrict__ x, const float* __restrict__ emb,
    const unsigned short* __restrict__ whi, const unsigned short* __restrict__ wlo,
    const float* __restrict__ wee,
    float* __restrict__ out_q, float* __restrict__ out_enc,
    float* __restrict__ out_dist, float* __restrict__ out_loss)
{
    __shared__ __align__(16) unsigned short ehi[2][32 * 64];  // 4 KB x2 dbuf, swizzled
    __shared__ __align__(16) unsigned short elo[2][32 * 64];  // 4 KB x2
    __shared__ __align__(16) float dtile[4][16 * DT];         // per-wave dist tile
    __shared__ __align__(16) float ee_s[512];                 // ||e_k||^2 (unscaled)
    __shared__ int   enc_s[64];
    __shared__ float red_s[4];

    const int t   = threadIdx.x;
    const int bid = blockIdx.x;              // 2048 blocks x 64 rows (rows = w)
    const int n_base = bid * 64;
    const size_t xbase = (size_t)(bid >> 6) * 262144 + (size_t)(bid & 63) * 64;
    const int l  = t & 63;
    const int wv = t >> 6;                   // 4 waves; wave owns rows wv*16..+15

    ee_s[t]       = wee[t];
    ee_s[t + 256] = wee[t + 256];

    // ---- x prologue: per-lane fragment load straight from global, no LDS ----
    // B layout (32x16): col = lane&15 (x row), d = (lane>>4)*8 + i  (+32 for frag1)
    const int myw = wv * 16 + (l & 15);      // this lane's row (= w)
    const int g8  = (l >> 4) * 8;
    float va[16];
    {
        const float* xp = x + xbase + myw;
        #pragma unroll
        for (int i = 0; i < 8; ++i) {
            va[i]     = xp[(size_t)(g8 + i) * 4096];
            va[8 + i] = xp[(size_t)(g8 + 32 + i) * 4096];
        }
    }
    short8 xhi0, xhi1, xlo0, xlo1;
    float xx = 0.f;
    #pragma unroll
    for (int i = 0; i < 8; ++i) {
        xx = fmaf(va[i], va[i], xx);
        xx = fmaf(va[8 + i], va[8 + i], xx);
        unsigned short hb = rne_bf16(va[i]);
        xhi0[i] = (short)hb; xlo0[i] = (short)rne_bf16(va[i] - bf16_to_f(hb));
        unsigned short hb2 = rne_bf16(va[8 + i]);
        xhi1[i] = (short)hb2; xlo1[i] = (short)rne_bf16(va[8 + i] - bf16_to_f(hb2));
    }
    xx += __shfl_xor(xx, 16, 64);            // 4 lane-groups cover disjoint d-ranges
    xx += __shfl_xor(xx, 32, 64);
    const f32x4 xx4 = {xx, xx, xx, xx};

    // ---- chunked (32 k-rows) double-buffered codebook staging ----
    short8 sh, sl;
    const int skr = t >> 3;                  // 0..31
    const int sd0 = (t & 7) * 8;
    const int sidx = skr * 64 + (sd0 ^ ((skr & 7) << 3));
    #define STAGE_LOAD(c) {                                                    \
        sh = *(const short8*)(whi + (size_t)(((c) * 32 + skr) * 64 + sd0));    \
        sl = *(const short8*)(wlo + (size_t)(((c) * 32 + skr) * 64 + sd0));    \
    }
    #define STAGE_WRITE(bufi) {                                                \
        *(short8*)&ehi[bufi][sidx] = sh;                                       \
        *(short8*)&elo[bufi][sidx] = sl;                                       \
    }

    STAGE_LOAD(0); STAGE_WRITE(0);
    float m1 = 3.4e38f, m2 = 3.4e38f; int k1 = 0;
    const int colb = (l >> 4) * 4;           // lane's k sub-base within a 16-k tile
    float* dwv = dtile[wv];
    __syncthreads();

    // ---- main loop: 16 chunks x 2 k-tiles; MFMA emits -2*dot; val IS dist ----
    #pragma unroll 2
    for (int c = 0; c < 16; ++c) {
        if (c < 15) STAGE_LOAD(c + 1);       // latency hides under compute
        const int bufi = c & 1;
        #pragma unroll
        for (int kti = 0; kti < 2; ++kti) {
            const int krl = kti * 16 + (l & 15);     // codebook row in chunk (A row)
            const int sw  = (krl & 7) << 3;
            const int bix = krl * 64;
            short8 ch0 = *(short8*)&ehi[bufi][bix + (g8 ^ sw)];
            short8 ch1 = *(short8*)&ehi[bufi][bix + ((g8 + 32) ^ sw)];
            short8 cl0 = *(short8*)&elo[bufi][bix + (g8 ^ sw)];
            short8 cl1 = *(short8*)&elo[bufi][bix + ((g8 + 32) ^ sw)];
            const int kb = c * 32 + kti * 16 + colb;   // lane's 4 k's: kb..kb+3
            f32x4 accA = *(const f32x4*)&ee_s[kb];     // init C = ||e||^2
            f32x4 accB = xx4;                          // init C = ||x||^2
            accA = MFMA(ch0, xhi0, accA);
            accB = MFMA(ch1, xhi1, accB);
            accA = MFMA(cl0, xhi0, accA);
            accB = MFMA(cl1, xhi1, accB);
            accA = MFMA(ch0, xlo0, accA);
            accB = MFMA(ch1, xlo1, accB);
            f32x4 dist4;
            #pragma unroll
            for (int r = 0; r < 4; ++r) {
                float dv = accA[r] + accB[r];          // xx + ee - 2*dot
                dist4[r] = dv;
                float nm2 = fmaxf(fminf(dv, m2), m1);  // med3(dv,m1,m2), m1<=m2
                k1 = (dv < m1) ? (kb | r) : k1;        // k ascending: strict < = first-min
                m1 = fminf(dv, m1);
                m2 = nm2;
            }
            // park in per-wave tile: row = l&15, quad = kti*4 + (l>>4)
            *(f32x4*)&dwv[(l & 15) * DT + (kti * 4 + (l >> 4)) * 4] = dist4;
        }
        // transpose-read + line-granular wave stores (8 rows x 128B per instr)
        #pragma unroll
        for (int p = 0; p < 2; ++p) {
            const int row = p * 8 + (l >> 3);
            const int k4  = (l & 7) * 4;
            f32x4 v = *(f32x4*)&dwv[row * DT + k4];
            *(f32x4*)(out_dist + (size_t)(n_base + wv * 16 + row) * 512 + c * 32 + k4) = v;
        }
        if (c < 15) STAGE_WRITE((c + 1) & 1);
        LIGHT_BARRIER();                     // LDS handoff only; stores stay in flight
    }

    __syncthreads();   // full drain: all dist stores visible for refine readback

    // ---- per-row argmin across the 4 k-lanes + rare candidate-only fp64 refine ----
    float* drow = out_dist + (size_t)(n_base + myw) * 512;
    float bv = m1; int bk = k1;
    {
        float ov = __shfl_xor(bv, 16, 64); int ok = __shfl_xor(bk, 16, 64);
        if (ov < bv || (ov == bv && ok < bk)) { bv = ov; bk = ok; }
        ov = __shfl_xor(bv, 32, 64); ok = __shfl_xor(bk, 32, 64);
        if (ov < bv || (ov == bv && ok < bk)) { bv = ov; bk = ok; }
    }
    const float thr = bv + EPS;
    const unsigned long long gmask = 0x0001000100010001ULL << (l & 15);
    unsigned long long b1 = __ballot(m1 <= thr);
    unsigned long long b2 = __ballot(m2 <= thr);
    int enc = bk; float lossv = bv;
    if (__popcll(b1 & gmask) > 1 || (b2 & gmask) != 0ULL) {   // column-coherent branch
        const float* dr   = drow + (l >> 4) * 128;
        const float* xcol = x + xbase + myw;
        double bestv = 1e300; int bestk = 0x7fffffff;
        #pragma unroll 1
        for (int c4 = 0; c4 < 32; ++c4) {
            float4 dv4 = *(const float4*)(dr + c4 * 4);
            float dvv[4] = {dv4.x, dv4.y, dv4.z, dv4.w};
            #pragma unroll 1
            for (int j = 0; j < 4; ++j) {
                if (dvv[j] <= thr) {
                    int k = (l >> 4) * 128 + c4 * 4 + j;
                    const float* er = emb + k * 64;
                    double s = 0.0;
                    #pragma unroll 4
                    for (int d = 0; d < 64; ++d) {
                        double df = (double)xcol[(size_t)d * 4096] - (double)er[d];
                        s += df * df;
                    }
                    if (s < bestv) { bestv = s; bestk = k; }  // ascending k, strict <
                }
            }
        }
        double ov = __shfl_xor(bestv, 16, 64); int ok = __shfl_xor(bestk, 16, 64);
        if (ov < bestv || (ov == bestv && ok < bestk)) { bestv = ov; bestk = ok; }
        ov = __shfl_xor(bestv, 32, 64); ok = __shfl_xor(bestk, 32, 64);
        if (ov < bestv || (ov == bestv && ok < bestk)) { bestv = ov; bestk = ok; }
        enc = bestk;
        if (l < 16 && enc != bk) lossv = drow[enc];
    }
    if (l < 16) {
        enc_s[myw] = enc;
        out_enc[n_base + myw] = (float)enc;
    }
    float lc = (l < 16) ? lossv : 0.f;       // row's (q-x)^2 sum == dist[row][enc]
    #pragma unroll
    for (int m = 32; m >= 1; m >>= 1) lc += __shfl_down(lc, m, 64);
    if (l == 0) red_s[wv] = lc;
    __syncthreads();
    if (t == 0)
        atomicAdd(out_loss, (red_s[0] + red_s[1] + red_s[2] + red_s[3]) * (1.0f / 8388608.0f));

    // ---- quantized gather (codebook L2-resident) + coalesced store ----
    {
        const int w  = t & 63;
        const int dg = t >> 6;               // d = dg*16..+15
        const int e  = enc_s[w];
        const float* er = emb + e * 64 + dg * 16;
        float* qp = out_q + xbase + (size_t)(dg * 16) * 4096 + w;
        #pragma unroll
        for (int qi = 0; qi < 4; ++qi) {
            float4 q4 = *(const float4*)(er + qi * 4);
            qp[(size_t)(qi * 4 + 0) * 4096] = q4.x;
            qp[(size_t)(qi * 4 + 1) * 4096] = q4.y;
            qp[(size_t)(qi * 4 + 2) * 4096] = q4.z;
            qp[(size_t)(qi * 4 + 3) * 4096] = q4.w;
        }
    }
}

extern "C" void kernel_launch(void* const* d_in, const int* in_sizes, int n_in,
                              void* d_out, int out_size, void* d_ws, size_t ws_size,
                              hipStream_t stream) {
    const float* x   = (const float*)d_in[0];   // [32,64,64,64]
    const float* emb = (const float*)d_in[1];   // [512,64]

    float* out_q    = (float*)d_out;            // 8388608
    float* out_enc  = out_q + 8388608;          // 131072
    float* out_dist = out_enc + 131072;         // 67108864
    float* out_loss = out_dist + 67108864;      // 1

    unsigned short* whi = (unsigned short*)d_ws;        // 512*64 bf16 hi of -2*emb (64 KB)
    unsigned short* wlo = whi + 32768;                  // 512*64 bf16 lo          (64 KB)
    float*          wee = (float*)(whi + 65536);        // 512 norms               (2 KB)

    hipMemsetAsync(out_loss, 0, sizeof(float), stream);
    prep_kernel<<<8, 64, 0, stream>>>(emb, whi, wlo, wee);
    vq_kernel<<<2048, 256, 0, stream>>>(x, emb, whi, wlo, wee,
                                        out_q, out_enc, out_dist, out_loss);
}